// Round 1
// baseline (268.131 us; speedup 1.0000x reference)
//
#include <hip/hip_runtime.h>
#include <cstdint>
#include <cstddef>

#define KBINS 2048
#define NDIMS 8
#define EPSF 1e-10f

__device__ inline float block_reduce_sum(float v) {
#pragma unroll
  for (int off = 32; off > 0; off >>= 1) v += __shfl_down(v, off, 64);
  __shared__ float smem[4];
  int lane = threadIdx.x & 63, wid = threadIdx.x >> 6;
  if (lane == 0) smem[wid] = v;
  __syncthreads();
  if (threadIdx.x == 0) {
    v = smem[0];
    int nw = ((int)blockDim.x + 63) >> 6;
    for (int w = 1; w < nw; ++w) v += smem[w];
  }
  return v;
}

__global__ void zero_u32(uint32_t* __restrict__ p, size_t n) {
  size_t i = (size_t)blockIdx.x * blockDim.x + threadIdx.x;
  size_t stride = (size_t)gridDim.x * blockDim.x;
  for (; i < n; i += stride) p[i] = 0u;
}

__global__ void zero_u4(uint4* __restrict__ p, size_t n4) {
  size_t i = (size_t)blockIdx.x * blockDim.x + threadIdx.x;
  size_t stride = (size_t)gridDim.x * blockDim.x;
  uint4 z; z.x = 0u; z.y = 0u; z.z = 0u; z.w = 0u;
  for (; i < n4; i += stride) p[i] = z;
}

// 8 marginal histograms, LDS-privatized (8*2048*4B = 64 KB LDS per block).
__global__ __launch_bounds__(256) void marg_hist(const int4* __restrict__ in4,
                                                 uint32_t* __restrict__ marg, int P) {
  __shared__ uint32_t h[NDIMS * KBINS];
  for (int i = threadIdx.x; i < NDIMS * KBINS; i += 256) h[i] = 0u;
  __syncthreads();
  int stride = gridDim.x * 256;
  for (int p = blockIdx.x * 256 + threadIdx.x; p < P; p += stride) {
    int4 a = in4[2 * p];
    int4 b = in4[2 * p + 1];
    atomicAdd(&h[0 * KBINS + a.x], 1u);
    atomicAdd(&h[1 * KBINS + a.y], 1u);
    atomicAdd(&h[2 * KBINS + a.z], 1u);
    atomicAdd(&h[3 * KBINS + a.w], 1u);
    atomicAdd(&h[4 * KBINS + b.x], 1u);
    atomicAdd(&h[5 * KBINS + b.y], 1u);
    atomicAdd(&h[6 * KBINS + b.z], 1u);
    atomicAdd(&h[7 * KBINS + b.w], 1u);
  }
  __syncthreads();
  for (int i = threadIdx.x; i < NDIMS * KBINS; i += 256) {
    uint32_t v = h[i];
    if (v) atomicAdd(&marg[i], v);
  }
}

__global__ void marg_entropy(const uint32_t* __restrict__ marg, float* __restrict__ Hd,
                             float invP) {
  int d = blockIdx.x;
  float acc = 0.0f;
  for (int i = threadIdx.x; i < KBINS; i += 256) {
    uint32_t c = marg[d * KBINS + i];
    if (c) {
      float pz = (float)c * invP;
      acc += pz * log2f(pz + EPSF);
    }
  }
  acc = block_reduce_sum(acc);
  if (threadIdx.x == 0) Hd[d] = -acc;
}

__device__ inline int sel8(const int4& a, const int4& b, int d) {
  switch (d) {
    case 0: return a.x;
    case 1: return a.y;
    case 2: return a.z;
    case 3: return a.w;
    case 4: return b.x;
    case 5: return b.y;
    case 6: return b.z;
    default: return b.w;
  }
}

// Joint histograms for tuples [t0, t0+C): one pass over points, C atomics each.
__global__ __launch_bounds__(256) void joint_hist(const int4* __restrict__ in4,
                                                  const int* __restrict__ tdims,
                                                  uint32_t* __restrict__ joint,
                                                  int t0, int C, int P) {
  int stride = gridDim.x * 256;
  for (int p = blockIdx.x * 256 + threadIdx.x; p < P; p += stride) {
    int4 a = in4[2 * p];
    int4 b = in4[2 * p + 1];
    for (int c = 0; c < C; ++c) {
      int d0 = tdims[(t0 + c) * 2 + 0];
      int d1 = tdims[(t0 + c) * 2 + 1];
      uint32_t i0 = (uint32_t)sel8(a, b, d0);
      uint32_t i1 = (uint32_t)sel8(a, b, d1);
      atomicAdd(&joint[(size_t)c * (KBINS * KBINS) + (size_t)(i0 * KBINS + i1)], 1u);
    }
  }
}

// blockIdx.y = tuple-in-chunk; grid-stride x over 4M bins as uint4.
__global__ __launch_bounds__(256) void joint_entropy(const uint4* __restrict__ joint4,
                                                     float* __restrict__ Hj,
                                                     int t0, float invP) {
  int c = blockIdx.y;
  const uint4* base = joint4 + (size_t)c * ((size_t)KBINS * KBINS / 4);
  const int n4 = KBINS * KBINS / 4;
  float acc = 0.0f;
  int stride = gridDim.x * 256;
  for (int i = blockIdx.x * 256 + threadIdx.x; i < n4; i += stride) {
    uint4 v = base[i];
    if (v.x) { float pz = (float)v.x * invP; acc += pz * log2f(pz + EPSF); }
    if (v.y) { float pz = (float)v.y * invP; acc += pz * log2f(pz + EPSF); }
    if (v.z) { float pz = (float)v.z * invP; acc += pz * log2f(pz + EPSF); }
    if (v.w) { float pz = (float)v.w * invP; acc += pz * log2f(pz + EPSF); }
  }
  acc = block_reduce_sum(acc);
  if (threadIdx.x == 0) atomicAdd(&Hj[t0 + c], -acc);
}

__global__ void finalize(const float* __restrict__ Hd, const float* __restrict__ Hj,
                         const int* __restrict__ tdims, int T, float* __restrict__ out) {
  if (threadIdx.x == 0 && blockIdx.x == 0) {
    float smi = 0.0f, shm = 0.0f, shj = 0.0f;
    for (int t = 0; t < T; ++t) {
      float Hm = Hd[tdims[2 * t]] + Hd[tdims[2 * t + 1]];
      float Hjv = Hj[t];
      smi += (Hm - Hjv) / Hm;
      shm += Hm;
      shj += Hjv;
    }
    float invT = 1.0f / (float)T;
    out[0] = smi * invT;
    out[1] = shm * invT;
    out[2] = shj * invT;
  }
}

extern "C" void kernel_launch(void* const* d_in, const int* in_sizes, int n_in,
                              void* d_out, int out_size, void* d_ws, size_t ws_size,
                              hipStream_t stream) {
  const int* inputs = (const int*)d_in[0];
  const int* tdims = (const int*)d_in[1];
  int P = in_sizes[0] / NDIMS;      // 262144
  int T = in_sizes[1] / 2;          // 10
  float invP = 1.0f / (float)P;

  char* ws = (char*)d_ws;
  uint32_t* marg = (uint32_t*)ws;                         // NDIMS*KBINS u32
  float* Hd = (float*)(ws + (size_t)NDIMS * KBINS * 4);   // NDIMS floats
  float* Hj = Hd + NDIMS;                                 // T floats
  size_t smallWords = (size_t)NDIMS * KBINS + NDIMS + T;
  size_t jointOff = ((size_t)NDIMS * KBINS * 4 + (size_t)(NDIMS + T) * 4 + 255) & ~(size_t)255;
  uint32_t* joint = (uint32_t*)(ws + jointOff);

  size_t JW = (size_t)KBINS * KBINS;                      // u32 words per tuple (4M)
  size_t availW = (ws_size > jointOff) ? (ws_size - jointOff) / 4 : 0;
  int C = (int)(availW / JW);
  if (C > T) C = T;
  if (C < 1) C = 1;   // hope ws fits at least one joint histogram

  zero_u32<<<64, 256, 0, stream>>>((uint32_t*)ws, smallWords);
  marg_hist<<<128, 256, 0, stream>>>((const int4*)inputs, marg, P);
  marg_entropy<<<NDIMS, 256, 0, stream>>>(marg, Hd, invP);

  for (int t0 = 0; t0 < T; t0 += C) {
    int cc = (T - t0 < C) ? (T - t0) : C;
    zero_u4<<<1024, 256, 0, stream>>>((uint4*)joint, (size_t)cc * JW / 4);
    joint_hist<<<(P + 255) / 256, 256, 0, stream>>>((const int4*)inputs, tdims, joint, t0, cc, P);
    dim3 g(512, cc, 1);
    joint_entropy<<<g, 256, 0, stream>>>((const uint4*)joint, Hj, t0, invP);
  }

  finalize<<<1, 64, 0, stream>>>(Hd, Hj, tdims, T, (float*)d_out);
}

// Round 2
// 166.878 us; speedup vs baseline: 1.6068x; 1.6068x over previous
//
#include <hip/hip_runtime.h>
#include <cstdint>
#include <cstddef>

#define KBINS 2048
#define NDIMS 8
#define EPSF 1e-10f
#define MAXT 10
#define CAP 4096           // slots per bucket (mean 2048, max ~2300 for uniform data)
#define CSTRIDE 16         // cursor padding: one u32 cursor per 64B line
#define NBUCK_MAX (MAXT * 128)
#define KEYSTRIDE 41       // 40 keys/thread padded to 41 to break LDS bank conflicts

__device__ inline float block_reduce_sum(float v) {
#pragma unroll
  for (int off = 32; off > 0; off >>= 1) v += __shfl_down(v, off, 64);
  __shared__ float smem[4];
  int lane = threadIdx.x & 63, wid = threadIdx.x >> 6;
  if (lane == 0) smem[wid] = v;
  __syncthreads();
  if (threadIdx.x == 0) {
    v = smem[0];
    int nw = ((int)blockDim.x + 63) >> 6;
    for (int w = 1; w < nw; ++w) v += smem[w];
  }
  return v;
}

__global__ void zero_u32(uint32_t* __restrict__ p, size_t n) {
  size_t i = (size_t)blockIdx.x * blockDim.x + threadIdx.x;
  size_t stride = (size_t)gridDim.x * blockDim.x;
  for (; i < n; i += stride) p[i] = 0u;
}

__device__ inline int sel8(const int4& a, const int4& b, int d) {
  switch (d) {
    case 0: return a.x;
    case 1: return a.y;
    case 2: return a.z;
    case 3: return a.w;
    case 4: return b.x;
    case 5: return b.y;
    case 6: return b.z;
    default: return b.w;
  }
}

// ---- Marginal path: private per-block hists (no global atomics) ----
__global__ __launch_bounds__(256) void marg_hist(const int4* __restrict__ in4,
                                                 uint32_t* __restrict__ priv, int P) {
  __shared__ uint32_t h[NDIMS * KBINS];  // 64 KB
  for (int i = threadIdx.x; i < NDIMS * KBINS; i += 256) h[i] = 0u;
  __syncthreads();
  int per = (P + gridDim.x - 1) / gridDim.x;
  int s = blockIdx.x * per;
  int e = min(P, s + per);
  for (int p = s + threadIdx.x; p < e; p += 256) {
    int4 a = in4[2 * p];
    int4 b = in4[2 * p + 1];
    atomicAdd(&h[0 * KBINS + a.x], 1u);
    atomicAdd(&h[1 * KBINS + a.y], 1u);
    atomicAdd(&h[2 * KBINS + a.z], 1u);
    atomicAdd(&h[3 * KBINS + a.w], 1u);
    atomicAdd(&h[4 * KBINS + b.x], 1u);
    atomicAdd(&h[5 * KBINS + b.y], 1u);
    atomicAdd(&h[6 * KBINS + b.z], 1u);
    atomicAdd(&h[7 * KBINS + b.w], 1u);
  }
  __syncthreads();
  uint32_t* dst = priv + (size_t)blockIdx.x * (NDIMS * KBINS);
  for (int i = threadIdx.x; i < NDIMS * KBINS; i += 256) dst[i] = h[i];
}

// 64 blocks x 256 threads = 16384 threads = one per marginal bin.
__global__ __launch_bounds__(256) void marg_entropy(const uint32_t* __restrict__ priv,
                                                    float* __restrict__ HdNeg,
                                                    float invP, int nb) {
  int gid = blockIdx.x * 256 + threadIdx.x;  // < 16384
  uint32_t c = 0;
  for (int b = 0; b < nb; ++b) c += priv[(size_t)b * (NDIMS * KBINS) + gid];
  float acc = 0.0f;
  if (c) {
    float pz = (float)c * invP;
    acc = pz * log2f(pz + EPSF);
  }
  acc = block_reduce_sum(acc);
  if (threadIdx.x == 0) atomicAdd(&HdNeg[gid >> 11], acc);  // block spans one dim
}

// ---- Joint path: bucket scatter with block-level reservation ----
// Each block: 1024 points, up to 40 keys/thread. Buckets = tuple*128 + (key22>>15).
__global__ __launch_bounds__(256) void scatter_kernel(const int4* __restrict__ in4,
                                                      const int* __restrict__ tdims,
                                                      uint32_t* __restrict__ gCursor,
                                                      uint16_t* __restrict__ bdata,
                                                      int P, int T) {
  __shared__ uint32_t cnt[NBUCK_MAX];
  __shared__ uint32_t base[NBUCK_MAX];
  __shared__ uint32_t keyBuf[256 * KEYSTRIDE];
  __shared__ int sdim[2 * MAXT];
  const int NB = T * 128;
  for (int i = threadIdx.x; i < NB; i += 256) cnt[i] = 0u;
  if (threadIdx.x < 2 * T) sdim[threadIdx.x] = tdims[threadIdx.x];
  __syncthreads();

  uint32_t* myBuf = &keyBuf[threadIdx.x * KEYSTRIDE];
  int nkeys = 0;
  int p0 = blockIdx.x * 1024 + threadIdx.x;
#pragma unroll
  for (int j = 0; j < 4; ++j) {
    int p = p0 + j * 256;
    if (p < P) {
      int4 a = in4[2 * p];
      int4 b = in4[2 * p + 1];
      for (int t = 0; t < T; ++t) {
        uint32_t i0 = (uint32_t)sel8(a, b, sdim[2 * t]);
        uint32_t i1 = (uint32_t)sel8(a, b, sdim[2 * t + 1]);
        uint32_t key22 = i0 * 2048u + i1;
        uint32_t bucket = (uint32_t)t * 128u + (key22 >> 15);
        atomicAdd(&cnt[bucket], 1u);
        myBuf[nkeys++] = (bucket << 15) | (key22 & 32767u);
      }
    }
  }
  __syncthreads();
  // one global reservation atomic per (block, bucket)
  for (int i = threadIdx.x; i < NB; i += 256) {
    uint32_t c = cnt[i];
    base[i] = c ? atomicAdd(&gCursor[i * CSTRIDE], c) : 0u;
  }
  __syncthreads();
  // replay: LDS cursor hands out global slots
  for (int k = 0; k < nkeys; ++k) {
    uint32_t key = myBuf[k];
    uint32_t bucket = key >> 15;
    uint32_t slot = atomicAdd(&base[bucket], 1u);
    if (slot < CAP) bdata[(size_t)bucket * CAP + slot] = (uint16_t)(key & 32767u);
  }
}

// One block per bucket: LDS histogram (32768 bins as packed u16 in 64KB) + entropy.
__global__ __launch_bounds__(256) void bucket_entropy(const uint16_t* __restrict__ bdata,
                                                      const uint32_t* __restrict__ gCursor,
                                                      float* __restrict__ HjNeg,
                                                      float invP) {
  __shared__ uint32_t hist[16384];  // 64 KB = 32768 u16 bins
  int b = blockIdx.x;
  int t = b >> 7;
  int n = (int)gCursor[b * CSTRIDE];
  if (n > CAP) n = CAP;
  for (int i = threadIdx.x; i < 16384; i += 256) hist[i] = 0u;
  __syncthreads();
  const uint16_t* data = bdata + (size_t)b * CAP;
  for (int i = threadIdx.x; i < n; i += 256) {
    uint32_t v = (uint32_t)data[i];
    atomicAdd(&hist[v >> 1], 1u << ((v & 1u) * 16u));
  }
  __syncthreads();
  float acc = 0.0f;
  for (int i = threadIdx.x; i < 16384; i += 256) {
    uint32_t w = hist[i];
    if (w) {
      uint32_t lo = w & 0xffffu, hi = w >> 16;
      if (lo) { float pz = (float)lo * invP; acc += pz * log2f(pz + EPSF); }
      if (hi) { float pz = (float)hi * invP; acc += pz * log2f(pz + EPSF); }
    }
  }
  __syncthreads();  // done reading hist; reuse it for the reduction
#pragma unroll
  for (int off = 32; off > 0; off >>= 1) acc += __shfl_down(acc, off, 64);
  int lane = threadIdx.x & 63, wid = threadIdx.x >> 6;
  if (lane == 0) ((float*)hist)[wid] = acc;
  __syncthreads();
  if (threadIdx.x == 0) {
    float* f = (float*)hist;
    atomicAdd(&HjNeg[t], f[0] + f[1] + f[2] + f[3]);
  }
}

__global__ void finalize(const float* __restrict__ HdNeg, const float* __restrict__ HjNeg,
                         const int* __restrict__ tdims, int T, float* __restrict__ out) {
  if (threadIdx.x == 0 && blockIdx.x == 0) {
    float smi = 0.0f, shm = 0.0f, shj = 0.0f;
    for (int t = 0; t < T; ++t) {
      float Hm = -(HdNeg[tdims[2 * t]] + HdNeg[tdims[2 * t + 1]]);
      float Hjv = -HjNeg[t];
      smi += (Hm - Hjv) / Hm;
      shm += Hm;
      shj += Hjv;
    }
    float invT = 1.0f / (float)T;
    out[0] = smi * invT;
    out[1] = shm * invT;
    out[2] = shj * invT;
  }
}

extern "C" void kernel_launch(void* const* d_in, const int* in_sizes, int n_in,
                              void* d_out, int out_size, void* d_ws, size_t ws_size,
                              hipStream_t stream) {
  const int* inputs = (const int*)d_in[0];
  const int* tdims = (const int*)d_in[1];
  int P = in_sizes[0] / NDIMS;  // 262144
  int T = in_sizes[1] / 2;      // 10
  if (T > MAXT) T = MAXT;
  float invP = 1.0f / (float)P;

  // ws layout
  char* ws = (char*)d_ws;
  uint32_t* gCursor = (uint32_t*)ws;                               // NBUCK_MAX*CSTRIDE u32
  size_t off = (size_t)NBUCK_MAX * CSTRIDE * 4;
  float* HdNeg = (float*)(ws + off); off += NDIMS * 4;
  float* HjNeg = (float*)(ws + off); off += MAXT * 4;
  size_t zeroWords = off / 4;                                       // contiguous zero region
  off = (off + 255) & ~(size_t)255;
  uint32_t* privMarg = (uint32_t*)(ws + off);                       // 64 * 16384 u32 = 4 MB
  off += (size_t)64 * NDIMS * KBINS * 4;
  off = (off + 255) & ~(size_t)255;
  uint16_t* bdata = (uint16_t*)(ws + off);                          // 1280*4096 u16 = 10 MB

  zero_u32<<<32, 256, 0, stream>>>(gCursor, zeroWords);
  marg_hist<<<64, 256, 0, stream>>>((const int4*)inputs, privMarg, P);
  marg_entropy<<<64, 256, 0, stream>>>(privMarg, HdNeg, invP, 64);
  scatter_kernel<<<(P + 1023) / 1024, 256, 0, stream>>>((const int4*)inputs, tdims,
                                                        gCursor, bdata, P, T);
  bucket_entropy<<<T * 128, 256, 0, stream>>>(bdata, gCursor, HjNeg, invP);
  finalize<<<1, 64, 0, stream>>>(HdNeg, HjNeg, tdims, T, (float*)d_out);
}

// Round 3
// 146.764 us; speedup vs baseline: 1.8270x; 1.1370x over previous
//
#include <hip/hip_runtime.h>
#include <cstdint>
#include <cstddef>

#define KBINS 2048
#define NDIMS 8
#define EPSF 1e-10f
#define MAXT 10
#define CAP 4096           // slots per bucket (mean 2048, max ~2300 for uniform data)
#define CSTRIDE 16         // cursor padding: one u32 cursor per 64B line
#define NBUCK (MAXT * 128) // 1280 buckets: tuple * 128 + top-7-bits(i0)
#define MARG_BLOCKS 256

__device__ inline float block_reduce_sum(float v) {
#pragma unroll
  for (int off = 32; off > 0; off >>= 1) v += __shfl_down(v, off, 64);
  __shared__ float smem[4];
  int lane = threadIdx.x & 63, wid = threadIdx.x >> 6;
  if (lane == 0) smem[wid] = v;
  __syncthreads();
  if (threadIdx.x == 0) {
    v = smem[0];
    int nw = ((int)blockDim.x + 63) >> 6;
    for (int w = 1; w < nw; ++w) v += smem[w];
  }
  return v;
}

__global__ void zero_u32(uint32_t* __restrict__ p, size_t n) {
  size_t i = (size_t)blockIdx.x * blockDim.x + threadIdx.x;
  size_t stride = (size_t)gridDim.x * blockDim.x;
  for (; i < n; i += stride) p[i] = 0u;
}

__device__ inline int sel8(const int4& a, const int4& b, int d) {
  switch (d) {
    case 0: return a.x;
    case 1: return a.y;
    case 2: return a.z;
    case 3: return a.w;
    case 4: return b.x;
    case 5: return b.y;
    case 6: return b.z;
    default: return b.w;
  }
}

// ---- Marginal path: private per-block hists (no global atomics) ----
__global__ __launch_bounds__(256) void marg_hist(const int4* __restrict__ in4,
                                                 uint32_t* __restrict__ priv, int P) {
  __shared__ uint32_t h[NDIMS * KBINS];  // 64 KB
  for (int i = threadIdx.x; i < NDIMS * KBINS; i += 256) h[i] = 0u;
  __syncthreads();
  int per = (P + gridDim.x - 1) / gridDim.x;
  int s = blockIdx.x * per;
  int e = min(P, s + per);
  for (int p = s + threadIdx.x; p < e; p += 256) {
    int4 a = in4[2 * p];
    int4 b = in4[2 * p + 1];
    atomicAdd(&h[0 * KBINS + a.x], 1u);
    atomicAdd(&h[1 * KBINS + a.y], 1u);
    atomicAdd(&h[2 * KBINS + a.z], 1u);
    atomicAdd(&h[3 * KBINS + a.w], 1u);
    atomicAdd(&h[4 * KBINS + b.x], 1u);
    atomicAdd(&h[5 * KBINS + b.y], 1u);
    atomicAdd(&h[6 * KBINS + b.z], 1u);
    atomicAdd(&h[7 * KBINS + b.w], 1u);
  }
  __syncthreads();
  uint32_t* dst = priv + (size_t)blockIdx.x * (NDIMS * KBINS);
  for (int i = threadIdx.x; i < NDIMS * KBINS; i += 256) dst[i] = h[i];
}

// 64 blocks x 256 threads = 16384 threads = one per marginal bin.
// Sums all MARG_BLOCKS private hists for its bin, then entropy-reduces.
__global__ __launch_bounds__(256) void marg_entropy(const uint32_t* __restrict__ priv,
                                                    float* __restrict__ HdNeg,
                                                    float invP) {
  int gid = blockIdx.x * 256 + threadIdx.x;  // < 16384
  uint32_t c0 = 0, c1 = 0, c2 = 0, c3 = 0;
  for (int b = 0; b < MARG_BLOCKS; b += 4) {
    c0 += priv[(size_t)(b + 0) * (NDIMS * KBINS) + gid];
    c1 += priv[(size_t)(b + 1) * (NDIMS * KBINS) + gid];
    c2 += priv[(size_t)(b + 2) * (NDIMS * KBINS) + gid];
    c3 += priv[(size_t)(b + 3) * (NDIMS * KBINS) + gid];
  }
  uint32_t c = c0 + c1 + c2 + c3;
  float acc = 0.0f;
  if (c) {
    float pz = (float)c * invP;
    acc = pz * __log2f(pz + EPSF);
  }
  acc = block_reduce_sum(acc);
  if (threadIdx.x == 0) atomicAdd(&HdNeg[gid >> 11], acc);  // block spans one dim
}

// ---- Joint path: bucket scatter, two passes over own input slice ----
// Block = 1024 points. Pass A: count per bucket in LDS. Reserve: one global
// atomic per (block,bucket). Pass B: recompute keys, write u16 payload.
__global__ __launch_bounds__(256) void scatter_kernel(const int4* __restrict__ in4,
                                                      const int* __restrict__ tdims,
                                                      uint32_t* __restrict__ gCursor,
                                                      uint16_t* __restrict__ bdata,
                                                      int P, int T) {
  __shared__ uint32_t cnt[NBUCK];
  __shared__ uint32_t base[NBUCK];
  __shared__ int sdim[2 * MAXT];
  const int NB = T * 128;
  for (int i = threadIdx.x; i < NB; i += 256) cnt[i] = 0u;
  if (threadIdx.x < 2 * T) sdim[threadIdx.x] = tdims[threadIdx.x];
  __syncthreads();

  int p0 = blockIdx.x * 1024 + threadIdx.x;
#pragma unroll
  for (int j = 0; j < 4; ++j) {
    int p = p0 + j * 256;
    if (p < P) {
      int4 a = in4[2 * p];
      int4 b = in4[2 * p + 1];
      for (int t = 0; t < T; ++t) {
        uint32_t i0 = (uint32_t)sel8(a, b, sdim[2 * t]);
        uint32_t i1 = (uint32_t)sel8(a, b, sdim[2 * t + 1]);
        uint32_t key22 = i0 * 2048u + i1;
        atomicAdd(&cnt[(uint32_t)t * 128u + (key22 >> 15)], 1u);
      }
    }
  }
  __syncthreads();
  // one global reservation atomic per (block, bucket)
  for (int i = threadIdx.x; i < NB; i += 256) {
    uint32_t c = cnt[i];
    base[i] = c ? atomicAdd(&gCursor[i * CSTRIDE], c) : 0u;
  }
  __syncthreads();
  // pass B: recompute keys (input slice is L1/L2-hot), hand out slots via LDS
#pragma unroll
  for (int j = 0; j < 4; ++j) {
    int p = p0 + j * 256;
    if (p < P) {
      int4 a = in4[2 * p];
      int4 b = in4[2 * p + 1];
      for (int t = 0; t < T; ++t) {
        uint32_t i0 = (uint32_t)sel8(a, b, sdim[2 * t]);
        uint32_t i1 = (uint32_t)sel8(a, b, sdim[2 * t + 1]);
        uint32_t key22 = i0 * 2048u + i1;
        uint32_t bucket = (uint32_t)t * 128u + (key22 >> 15);
        uint32_t slot = atomicAdd(&base[bucket], 1u);
        if (slot < CAP) bdata[(size_t)bucket * CAP + slot] = (uint16_t)(key22 & 32767u);
      }
    }
  }
}

// One block per bucket. Phase 1: LDS histogram (32768 bins packed u16 = 64KB).
// Phase 2: revisit the keys — each key contributes log2(c_bin/P + eps).
// (Identity: sum_bins c*log2(c/P+eps) == sum_keys log2(c_bin(key)/P+eps).)
__global__ __launch_bounds__(256) void bucket_entropy(const uint16_t* __restrict__ bdata,
                                                      const uint32_t* __restrict__ gCursor,
                                                      float* __restrict__ HjNeg,
                                                      float invP) {
  __shared__ uint32_t hist[16384];  // 64 KB = 32768 u16 bins
  int b = blockIdx.x;
  int t = b >> 7;
  int n = (int)gCursor[b * CSTRIDE];
  if (n > CAP) n = CAP;
  for (int i = threadIdx.x; i < 16384; i += 256) hist[i] = 0u;
  __syncthreads();
  const uint16_t* data = bdata + (size_t)b * CAP;
  for (int i = threadIdx.x; i < n; i += 256) {
    uint32_t v = (uint32_t)data[i];
    atomicAdd(&hist[v >> 1], 1u << ((v & 1u) * 16u));
  }
  __syncthreads();
  float acc = 0.0f;
  for (int i = threadIdx.x; i < n; i += 256) {
    uint32_t v = (uint32_t)data[i];          // L1/L2-hot re-read
    uint32_t w = hist[v >> 1];
    uint32_t c = (v & 1u) ? (w >> 16) : (w & 0xffffu);
    acc += __log2f((float)c * invP + EPSF);
  }
  __syncthreads();  // done with hist; reuse for the reduction
#pragma unroll
  for (int off = 32; off > 0; off >>= 1) acc += __shfl_down(acc, off, 64);
  int lane = threadIdx.x & 63, wid = threadIdx.x >> 6;
  if (lane == 0) ((float*)hist)[wid] = acc;
  __syncthreads();
  if (threadIdx.x == 0) {
    float* f = (float*)hist;
    atomicAdd(&HjNeg[t], f[0] + f[1] + f[2] + f[3]);
  }
}

__global__ void finalize(const float* __restrict__ HdNeg, const float* __restrict__ HjNeg,
                         const int* __restrict__ tdims, int T, float invP,
                         float* __restrict__ out) {
  if (threadIdx.x == 0 && blockIdx.x == 0) {
    float smi = 0.0f, shm = 0.0f, shj = 0.0f;
    for (int t = 0; t < T; ++t) {
      float Hm = -(HdNeg[tdims[2 * t]] + HdNeg[tdims[2 * t + 1]]);
      float Hjv = -HjNeg[t] * invP;
      smi += (Hm - Hjv) / Hm;
      shm += Hm;
      shj += Hjv;
    }
    float invT = 1.0f / (float)T;
    out[0] = smi * invT;
    out[1] = shm * invT;
    out[2] = shj * invT;
  }
}

extern "C" void kernel_launch(void* const* d_in, const int* in_sizes, int n_in,
                              void* d_out, int out_size, void* d_ws, size_t ws_size,
                              hipStream_t stream) {
  const int* inputs = (const int*)d_in[0];
  const int* tdims = (const int*)d_in[1];
  int P = in_sizes[0] / NDIMS;  // 262144
  int T = in_sizes[1] / 2;      // 10
  if (T > MAXT) T = MAXT;
  float invP = 1.0f / (float)P;

  // ws layout
  char* ws = (char*)d_ws;
  uint32_t* gCursor = (uint32_t*)ws;                               // NBUCK*CSTRIDE u32
  size_t off = (size_t)NBUCK * CSTRIDE * 4;
  float* HdNeg = (float*)(ws + off); off += NDIMS * 4;
  float* HjNeg = (float*)(ws + off); off += MAXT * 4;
  size_t zeroWords = off / 4;                                      // contiguous zero region
  off = (off + 255) & ~(size_t)255;
  uint32_t* privMarg = (uint32_t*)(ws + off);                      // 256 * 16384 u32 = 16 MB
  off += (size_t)MARG_BLOCKS * NDIMS * KBINS * 4;
  off = (off + 255) & ~(size_t)255;
  uint16_t* bdata = (uint16_t*)(ws + off);                         // 1280*4096 u16 = 10 MB

  zero_u32<<<32, 256, 0, stream>>>(gCursor, zeroWords);
  marg_hist<<<MARG_BLOCKS, 256, 0, stream>>>((const int4*)inputs, privMarg, P);
  marg_entropy<<<64, 256, 0, stream>>>(privMarg, HdNeg, invP);
  scatter_kernel<<<(P + 1023) / 1024, 256, 0, stream>>>((const int4*)inputs, tdims,
                                                        gCursor, bdata, P, T);
  bucket_entropy<<<T * 128, 256, 0, stream>>>(bdata, gCursor, HjNeg, invP);
  finalize<<<1, 64, 0, stream>>>(HdNeg, HjNeg, tdims, T, invP, (float*)d_out);
}

// Round 4
// 130.792 us; speedup vs baseline: 2.0501x; 1.1221x over previous
//
#include <hip/hip_runtime.h>
#include <cstdint>
#include <cstddef>

#define KBINS 2048
#define NDIMS 8
#define EPSF 1e-10f
#define MAXT 10
#define BPT 64                 // buckets per tuple: top-6 bits of key22
#define NBUCK (MAXT * BPT)     // 640
#define CAP 6144               // slots/bucket (mean 4096, std ~64 -> 32 sigma slack)
#define CSTRIDE 16             // one cursor per 64B line
#define MARG_BLOCKS 128
#define MARG_WORDS (NDIMS * KBINS / 2)  // 8192 u32 words of packed u16 pairs

__device__ inline float block_reduce_sum(float v) {
#pragma unroll
  for (int off = 32; off > 0; off >>= 1) v += __shfl_down(v, off, 64);
  __shared__ float smem[4];
  int lane = threadIdx.x & 63, wid = threadIdx.x >> 6;
  if (lane == 0) smem[wid] = v;
  __syncthreads();
  if (threadIdx.x == 0) {
    v = smem[0];
    int nw = ((int)blockDim.x + 63) >> 6;
    for (int w = 1; w < nw; ++w) v += smem[w];
  }
  return v;
}

__global__ void zero_u32(uint32_t* __restrict__ p, size_t n) {
  size_t i = (size_t)blockIdx.x * blockDim.x + threadIdx.x;
  size_t stride = (size_t)gridDim.x * blockDim.x;
  for (; i < n; i += stride) p[i] = 0u;
}

__device__ inline int sel8(const int4& a, const int4& b, int d) {
  switch (d) {
    case 0: return a.x;
    case 1: return a.y;
    case 2: return a.z;
    case 3: return a.w;
    case 4: return b.x;
    case 5: return b.y;
    case 6: return b.z;
    default: return b.w;
  }
}

// ---- Marginal path: u16-packed private per-block hists (32 KB LDS) ----
__global__ __launch_bounds__(256) void marg_hist(const int4* __restrict__ in4,
                                                 uint32_t* __restrict__ priv, int P) {
  __shared__ uint32_t h[MARG_WORDS];  // 32 KB: 16384 u16 bins
  uint4* h4 = (uint4*)h;
  for (int i = threadIdx.x; i < MARG_WORDS / 4; i += 256) {
    uint4 z; z.x = 0; z.y = 0; z.z = 0; z.w = 0;
    h4[i] = z;
  }
  __syncthreads();
  int per = (P + gridDim.x - 1) / gridDim.x;  // 2048 (counts fit u16)
  int s = blockIdx.x * per;
  int e = min(P, s + per);
  for (int p = s + threadIdx.x; p < e; p += 256) {
    int4 a = in4[2 * p];
    int4 b = in4[2 * p + 1];
    // bin = d*2048 + v -> word = d*1024 + (v>>1), half = v&1
    atomicAdd(&h[0 * 1024 + (a.x >> 1)], 1u << ((a.x & 1) * 16));
    atomicAdd(&h[1 * 1024 + (a.y >> 1)], 1u << ((a.y & 1) * 16));
    atomicAdd(&h[2 * 1024 + (a.z >> 1)], 1u << ((a.z & 1) * 16));
    atomicAdd(&h[3 * 1024 + (a.w >> 1)], 1u << ((a.w & 1) * 16));
    atomicAdd(&h[4 * 1024 + (b.x >> 1)], 1u << ((b.x & 1) * 16));
    atomicAdd(&h[5 * 1024 + (b.y >> 1)], 1u << ((b.y & 1) * 16));
    atomicAdd(&h[6 * 1024 + (b.z >> 1)], 1u << ((b.z & 1) * 16));
    atomicAdd(&h[7 * 1024 + (b.w >> 1)], 1u << ((b.w & 1) * 16));
  }
  __syncthreads();
  uint32_t* dst = priv + (size_t)blockIdx.x * MARG_WORDS;
  for (int i = threadIdx.x; i < MARG_WORDS; i += 256) dst[i] = h[i];
}

// 32 blocks x 256 threads = 8192 threads: one packed-pair word column each.
// Block b covers words [b*256,(b+1)*256) -> dim = b>>2 (1024 words per dim).
__global__ __launch_bounds__(256) void marg_entropy(const uint32_t* __restrict__ priv,
                                                    float* __restrict__ HdNeg,
                                                    float invP) {
  int col = blockIdx.x * 256 + threadIdx.x;  // < 8192
  uint32_t lo = 0, hi = 0;
  for (int r = 0; r < MARG_BLOCKS; r += 4) {
    uint32_t w0 = priv[(size_t)(r + 0) * MARG_WORDS + col];
    uint32_t w1 = priv[(size_t)(r + 1) * MARG_WORDS + col];
    uint32_t w2 = priv[(size_t)(r + 2) * MARG_WORDS + col];
    uint32_t w3 = priv[(size_t)(r + 3) * MARG_WORDS + col];
    lo += (w0 & 0xffffu) + (w1 & 0xffffu) + (w2 & 0xffffu) + (w3 & 0xffffu);
    hi += (w0 >> 16) + (w1 >> 16) + (w2 >> 16) + (w3 >> 16);
  }
  float acc = 0.0f;
  if (lo) { float pz = (float)lo * invP; acc += pz * __log2f(pz + EPSF); }
  if (hi) { float pz = (float)hi * invP; acc += pz * __log2f(pz + EPSF); }
  acc = block_reduce_sum(acc);
  if (threadIdx.x == 0) atomicAdd(&HdNeg[blockIdx.x >> 2], acc);
}

// ---- Joint path: bucket scatter, 512 pts/block, two passes over own slice ----
__global__ __launch_bounds__(256) void scatter_kernel(const int4* __restrict__ in4,
                                                      const int* __restrict__ tdims,
                                                      uint32_t* __restrict__ gCursor,
                                                      uint16_t* __restrict__ bdata,
                                                      int P, int T) {
  __shared__ uint32_t cnt[NBUCK];
  __shared__ uint32_t base[NBUCK];
  __shared__ int sdim[2 * MAXT];
  const int NB = T * BPT;
  for (int i = threadIdx.x; i < NB; i += 256) cnt[i] = 0u;
  if (threadIdx.x < 2 * T) sdim[threadIdx.x] = tdims[threadIdx.x];
  __syncthreads();

  int p0 = blockIdx.x * 512 + threadIdx.x;
#pragma unroll
  for (int j = 0; j < 2; ++j) {
    int p = p0 + j * 256;
    if (p < P) {
      int4 a = in4[2 * p];
      int4 b = in4[2 * p + 1];
      for (int t = 0; t < T; ++t) {
        uint32_t i0 = (uint32_t)sel8(a, b, sdim[2 * t]);
        uint32_t i1 = (uint32_t)sel8(a, b, sdim[2 * t + 1]);
        uint32_t key22 = i0 * 2048u + i1;
        atomicAdd(&cnt[(uint32_t)t * BPT + (key22 >> 16)], 1u);
      }
    }
  }
  __syncthreads();
  for (int i = threadIdx.x; i < NB; i += 256) {
    uint32_t c = cnt[i];
    base[i] = c ? atomicAdd(&gCursor[i * CSTRIDE], c) : 0u;
  }
  __syncthreads();
#pragma unroll
  for (int j = 0; j < 2; ++j) {
    int p = p0 + j * 256;
    if (p < P) {
      int4 a = in4[2 * p];
      int4 b = in4[2 * p + 1];
      for (int t = 0; t < T; ++t) {
        uint32_t i0 = (uint32_t)sel8(a, b, sdim[2 * t]);
        uint32_t i1 = (uint32_t)sel8(a, b, sdim[2 * t + 1]);
        uint32_t key22 = i0 * 2048u + i1;
        uint32_t bucket = (uint32_t)t * BPT + (key22 >> 16);
        uint32_t slot = atomicAdd(&base[bucket], 1u);
        if (slot < CAP) bdata[(size_t)bucket * CAP + slot] = (uint16_t)(key22 & 0xffffu);
      }
    }
  }
}

// One block per bucket (640 total). 65536 u8 bins packed in 64 KB LDS.
// Entropy via key-revisit identity: sum_keys log2(c_bin(key)/P + eps).
__global__ __launch_bounds__(256) void bucket_entropy(const uint16_t* __restrict__ bdata,
                                                      const uint32_t* __restrict__ gCursor,
                                                      float* __restrict__ HjNeg,
                                                      float invP) {
  __shared__ uint32_t hist[16384];  // 64 KB
  int b = blockIdx.x;
  int t = b / BPT;
  int n = (int)gCursor[b * CSTRIDE];
  if (n > CAP) n = CAP;
  uint4* h4 = (uint4*)hist;
  for (int i = threadIdx.x; i < 4096; i += 256) {
    uint4 z; z.x = 0; z.y = 0; z.z = 0; z.w = 0;
    h4[i] = z;
  }
  __syncthreads();
  const uint16_t* data = bdata + (size_t)b * CAP;
  for (int i = threadIdx.x; i < n; i += 256) {
    uint32_t v = (uint32_t)data[i];
    atomicAdd(&hist[v >> 2], 1u << ((v & 3u) * 8u));
  }
  __syncthreads();
  float acc = 0.0f;
  for (int i = threadIdx.x; i < n; i += 256) {
    uint32_t v = (uint32_t)data[i];  // L1-hot re-read
    uint32_t c = (hist[v >> 2] >> ((v & 3u) * 8u)) & 255u;
    acc += __log2f((float)c * invP + EPSF);
  }
  __syncthreads();  // done with hist; reuse for reduction
#pragma unroll
  for (int off = 32; off > 0; off >>= 1) acc += __shfl_down(acc, off, 64);
  int lane = threadIdx.x & 63, wid = threadIdx.x >> 6;
  if (lane == 0) ((float*)hist)[wid] = acc;
  __syncthreads();
  if (threadIdx.x == 0) {
    float* f = (float*)hist;
    atomicAdd(&HjNeg[t], f[0] + f[1] + f[2] + f[3]);
  }
}

__global__ void finalize(const float* __restrict__ HdNeg, const float* __restrict__ HjNeg,
                         const int* __restrict__ tdims, int T, float invP,
                         float* __restrict__ out) {
  if (threadIdx.x == 0 && blockIdx.x == 0) {
    float smi = 0.0f, shm = 0.0f, shj = 0.0f;
    for (int t = 0; t < T; ++t) {
      float Hm = -(HdNeg[tdims[2 * t]] + HdNeg[tdims[2 * t + 1]]);
      float Hjv = -HjNeg[t] * invP;
      smi += (Hm - Hjv) / Hm;
      shm += Hm;
      shj += Hjv;
    }
    float invT = 1.0f / (float)T;
    out[0] = smi * invT;
    out[1] = shm * invT;
    out[2] = shj * invT;
  }
}

extern "C" void kernel_launch(void* const* d_in, const int* in_sizes, int n_in,
                              void* d_out, int out_size, void* d_ws, size_t ws_size,
                              hipStream_t stream) {
  const int* inputs = (const int*)d_in[0];
  const int* tdims = (const int*)d_in[1];
  int P = in_sizes[0] / NDIMS;  // 262144
  int T = in_sizes[1] / 2;      // 10
  if (T > MAXT) T = MAXT;
  float invP = 1.0f / (float)P;

  // ws layout
  char* ws = (char*)d_ws;
  uint32_t* gCursor = (uint32_t*)ws;                            // NBUCK*CSTRIDE u32 = 40 KB
  size_t off = (size_t)NBUCK * CSTRIDE * 4;
  float* HdNeg = (float*)(ws + off); off += NDIMS * 4;
  float* HjNeg = (float*)(ws + off); off += MAXT * 4;
  size_t zeroWords = off / 4;                                   // contiguous zero region
  off = (off + 255) & ~(size_t)255;
  uint32_t* privMarg = (uint32_t*)(ws + off);                   // 128 * 32 KB = 4 MB
  off += (size_t)MARG_BLOCKS * MARG_WORDS * 4;
  off = (off + 255) & ~(size_t)255;
  uint16_t* bdata = (uint16_t*)(ws + off);                      // 640*6144 u16 = 7.9 MB

  zero_u32<<<40, 256, 0, stream>>>(gCursor, zeroWords);
  marg_hist<<<MARG_BLOCKS, 256, 0, stream>>>((const int4*)inputs, privMarg, P);
  marg_entropy<<<32, 256, 0, stream>>>(privMarg, HdNeg, invP);
  scatter_kernel<<<(P + 511) / 512, 256, 0, stream>>>((const int4*)inputs, tdims,
                                                      gCursor, bdata, P, T);
  bucket_entropy<<<T * BPT, 256, 0, stream>>>(bdata, gCursor, HjNeg, invP);
  finalize<<<1, 64, 0, stream>>>(HdNeg, HjNeg, tdims, T, invP, (float*)d_out);
}

// Round 5
// 121.199 us; speedup vs baseline: 2.2123x; 1.0792x over previous
//
#include <hip/hip_runtime.h>
#include <cstdint>
#include <cstddef>

#define KBINS 2048
#define NDIMS 8
#define EPSF 1e-10f
#define MAXT 10
#define BPT 64                  // buckets per tuple: top-6 bits of key22
#define NBUCK (MAXT * BPT)      // 640 max
#define NGRP 8                  // XCD groups (blockIdx & 7)
#define CAP_SEG 768             // slots per (group,bucket); mean 512, sigma ~23
#define CSTRIDE 4               // cursor padding (16 B apart)
#define MARG_BLOCKS 128
#define MARG_WORDS (NDIMS * KBINS / 2)  // 8192 u32 words of packed u16 pairs

__device__ inline float block_reduce_sum(float v) {
#pragma unroll
  for (int off = 32; off > 0; off >>= 1) v += __shfl_down(v, off, 64);
  __shared__ float smem[4];
  int lane = threadIdx.x & 63, wid = threadIdx.x >> 6;
  if (lane == 0) smem[wid] = v;
  __syncthreads();
  if (threadIdx.x == 0) {
    v = smem[0];
    int nw = ((int)blockDim.x + 63) >> 6;
    for (int w = 1; w < nw; ++w) v += smem[w];
  }
  return v;
}

__device__ inline int sel8(const int4& a, const int4& b, int d) {
  switch (d) {
    case 0: return a.x;
    case 1: return a.y;
    case 2: return a.z;
    case 3: return a.w;
    case 4: return b.x;
    case 5: return b.y;
    case 6: return b.z;
    default: return b.w;
  }
}

// ---- Kernel 1: zero the cursor/accumulator region + marginal private hists ----
__global__ __launch_bounds__(256) void marg_zero_hist(const int4* __restrict__ in4,
                                                      uint32_t* __restrict__ priv,
                                                      uint32_t* __restrict__ zreg,
                                                      int zwords, int P) {
  // grid-stride zero of cursors + HdNeg + HjNeg + done
  for (int i = blockIdx.x * 256 + threadIdx.x; i < zwords; i += gridDim.x * 256)
    zreg[i] = 0u;

  __shared__ uint32_t h[MARG_WORDS];  // 32 KB: 16384 u16 bins
  uint4* h4 = (uint4*)h;
  for (int i = threadIdx.x; i < MARG_WORDS / 4; i += 256) {
    uint4 z; z.x = 0; z.y = 0; z.z = 0; z.w = 0;
    h4[i] = z;
  }
  __syncthreads();
  int per = (P + gridDim.x - 1) / gridDim.x;  // 2048 -> counts fit u16
  int s = blockIdx.x * per;
  int e = min(P, s + per);
  for (int p = s + threadIdx.x; p < e; p += 256) {
    int4 a = in4[2 * p];
    int4 b = in4[2 * p + 1];
    atomicAdd(&h[0 * 1024 + (a.x >> 1)], 1u << ((a.x & 1) * 16));
    atomicAdd(&h[1 * 1024 + (a.y >> 1)], 1u << ((a.y & 1) * 16));
    atomicAdd(&h[2 * 1024 + (a.z >> 1)], 1u << ((a.z & 1) * 16));
    atomicAdd(&h[3 * 1024 + (a.w >> 1)], 1u << ((a.w & 1) * 16));
    atomicAdd(&h[4 * 1024 + (b.x >> 1)], 1u << ((b.x & 1) * 16));
    atomicAdd(&h[5 * 1024 + (b.y >> 1)], 1u << ((b.y & 1) * 16));
    atomicAdd(&h[6 * 1024 + (b.z >> 1)], 1u << ((b.z & 1) * 16));
    atomicAdd(&h[7 * 1024 + (b.w >> 1)], 1u << ((b.w & 1) * 16));
  }
  __syncthreads();
  uint32_t* dst = priv + (size_t)blockIdx.x * MARG_WORDS;
  for (int i = threadIdx.x; i < MARG_WORDS; i += 256) dst[i] = h[i];
}

// ---- Kernel 2: bucket scatter (1 pt/thread, unrolled tuples, XCD-grouped
//      segments) + fused marginal entropy on blocks 0..31 ----
__global__ __launch_bounds__(256) void scatter_marg(const int4* __restrict__ in4,
                                                    const int* __restrict__ tdims,
                                                    const uint32_t* __restrict__ privMarg,
                                                    float* __restrict__ HdNeg,
                                                    uint32_t* __restrict__ gCursor,
                                                    uint16_t* __restrict__ bdata,
                                                    int P, int T, float invP) {
  __shared__ uint32_t cnt[NBUCK];
  __shared__ uint32_t base[NBUCK];
  __shared__ int sdim[2 * MAXT];
  const int NB = T * BPT;
  for (int i = threadIdx.x; i < NB; i += 256) cnt[i] = 0u;
  if (threadIdx.x < 2 * T) sdim[threadIdx.x] = tdims[threadIdx.x];
  __syncthreads();

  // fused marginal entropy (32 blocks x 256 thr = 8192 packed-word columns)
  if (blockIdx.x < 32) {
    int col = blockIdx.x * 256 + threadIdx.x;
    uint32_t lo = 0, hi = 0;
    for (int r = 0; r < MARG_BLOCKS; r += 4) {
      uint32_t w0 = privMarg[(size_t)(r + 0) * MARG_WORDS + col];
      uint32_t w1 = privMarg[(size_t)(r + 1) * MARG_WORDS + col];
      uint32_t w2 = privMarg[(size_t)(r + 2) * MARG_WORDS + col];
      uint32_t w3 = privMarg[(size_t)(r + 3) * MARG_WORDS + col];
      lo += (w0 & 0xffffu) + (w1 & 0xffffu) + (w2 & 0xffffu) + (w3 & 0xffffu);
      hi += (w0 >> 16) + (w1 >> 16) + (w2 >> 16) + (w3 >> 16);
    }
    float acc = 0.0f;
    if (lo) { float pz = (float)lo * invP; acc += pz * __log2f(pz + EPSF); }
    if (hi) { float pz = (float)hi * invP; acc += pz * __log2f(pz + EPSF); }
    acc = block_reduce_sum(acc);
    if (threadIdx.x == 0) atomicAdd(&HdNeg[blockIdx.x >> 2], acc);
  }

  int p = blockIdx.x * 256 + threadIdx.x;
  uint32_t g = blockIdx.x & (NGRP - 1);
  bool valid = p < P;
  int4 a, b;
  if (valid) { a = in4[2 * p]; b = in4[2 * p + 1]; }
  uint32_t key[MAXT];  // (bucket<<16) | low16-of-key22
#pragma unroll
  for (int t = 0; t < MAXT; ++t) {
    if (t < T && valid) {
      uint32_t i0 = (uint32_t)sel8(a, b, sdim[2 * t]);
      uint32_t i1 = (uint32_t)sel8(a, b, sdim[2 * t + 1]);
      uint32_t key22 = i0 * 2048u + i1;
      key[t] = (((uint32_t)t * BPT + (key22 >> 16)) << 16) | (key22 & 0xffffu);
      atomicAdd(&cnt[key[t] >> 16], 1u);  // no-return LDS add
    }
  }
  __syncthreads();
  // one global reservation atomic per (block,bucket), into this group's cursors
  for (int i = threadIdx.x; i < NB; i += 256) {
    uint32_t c = cnt[i];
    base[i] = c ? atomicAdd(&gCursor[((size_t)g * NB + i) * CSTRIDE], c) : 0u;
  }
  __syncthreads();
#pragma unroll
  for (int t = 0; t < MAXT; ++t) {
    if (t < T && valid) {
      uint32_t bkt = key[t] >> 16;
      uint32_t slot = atomicAdd(&base[bkt], 1u);
      if (slot < CAP_SEG)
        bdata[((size_t)g * NB + bkt) * CAP_SEG + slot] = (uint16_t)(key[t] & 0xffffu);
    }
  }
}

// ---- Kernel 3: per-bucket entropy (u8 hist, 64 KB LDS) + fused finalize ----
__global__ __launch_bounds__(256) void bucket_entropy_fin(
    const uint16_t* __restrict__ bdata, const uint32_t* __restrict__ gCursor,
    float* __restrict__ HjNeg, const float* __restrict__ HdNeg,
    const int* __restrict__ tdims, uint32_t* __restrict__ done,
    int T, float invP, float* __restrict__ out) {
  __shared__ uint32_t hist[16384];  // 64 KB = 65536 u8 bins
  int b = blockIdx.x;
  int t = b / BPT;
  const int NB = T * BPT;
  uint4* h4 = (uint4*)hist;
  for (int i = threadIdx.x; i < 4096; i += 256) {
    uint4 z; z.x = 0; z.y = 0; z.z = 0; z.w = 0;
    h4[i] = z;
  }
  __syncthreads();
  int n[NGRP];
#pragma unroll
  for (int g = 0; g < NGRP; ++g) {
    int v = (int)gCursor[((size_t)g * NB + b) * CSTRIDE];
    n[g] = v < CAP_SEG ? v : CAP_SEG;
  }
#pragma unroll
  for (int g = 0; g < NGRP; ++g) {
    const uint16_t* d = bdata + ((size_t)g * NB + b) * CAP_SEG;
    for (int i = threadIdx.x; i < n[g]; i += 256) {
      uint32_t v = (uint32_t)d[i];
      atomicAdd(&hist[v >> 2], 1u << ((v & 3u) * 8u));
    }
  }
  __syncthreads();
  float acc = 0.0f;
#pragma unroll
  for (int g = 0; g < NGRP; ++g) {
    const uint16_t* d = bdata + ((size_t)g * NB + b) * CAP_SEG;
    for (int i = threadIdx.x; i < n[g]; i += 256) {
      uint32_t v = (uint32_t)d[i];  // L1/L2-hot re-read
      uint32_t c = (hist[v >> 2] >> ((v & 3u) * 8u)) & 255u;
      acc += __log2f((float)c * invP + EPSF);
    }
  }
  acc = block_reduce_sum(acc);
  if (threadIdx.x == 0) {
    atomicAdd(&HjNeg[t], acc);
    __threadfence();
    uint32_t old = atomicAdd(done, 1u);
    if (old == (uint32_t)(NB - 1)) {  // last bucket: finalize
      __threadfence();
      float smi = 0.0f, shm = 0.0f, shj = 0.0f;
      for (int tt = 0; tt < T; ++tt) {
        float Hm = -(HdNeg[tdims[2 * tt]] + HdNeg[tdims[2 * tt + 1]]);
        float Hjv = -atomicAdd(&HjNeg[tt], 0.0f) * invP;  // coherent read
        smi += (Hm - Hjv) / Hm;
        shm += Hm;
        shj += Hjv;
      }
      float invT = 1.0f / (float)T;
      out[0] = smi * invT;
      out[1] = shm * invT;
      out[2] = shj * invT;
    }
  }
}

extern "C" void kernel_launch(void* const* d_in, const int* in_sizes, int n_in,
                              void* d_out, int out_size, void* d_ws, size_t ws_size,
                              hipStream_t stream) {
  const int* inputs = (const int*)d_in[0];
  const int* tdims = (const int*)d_in[1];
  int P = in_sizes[0] / NDIMS;  // 262144
  int T = in_sizes[1] / 2;      // 10
  if (T > MAXT) T = MAXT;
  float invP = 1.0f / (float)P;

  // ws layout: [gCursor | HdNeg | HjNeg | done]  (zeroed by kernel 1)
  char* ws = (char*)d_ws;
  uint32_t* gCursor = (uint32_t*)ws;                      // NGRP*NBUCK*CSTRIDE u32 = 80 KB
  size_t off = (size_t)NGRP * NBUCK * CSTRIDE * 4;
  float* HdNeg = (float*)(ws + off); off += NDIMS * 4;
  float* HjNeg = (float*)(ws + off); off += MAXT * 4;
  uint32_t* done = (uint32_t*)(ws + off); off += 4;
  int zwords = (int)(off / 4);
  off = (off + 255) & ~(size_t)255;
  uint32_t* privMarg = (uint32_t*)(ws + off);             // 128 * 32 KB = 4 MB
  off += (size_t)MARG_BLOCKS * MARG_WORDS * 4;
  off = (off + 255) & ~(size_t)255;
  uint16_t* bdata = (uint16_t*)(ws + off);                // 8*640*768*2 = 7.86 MB

  marg_zero_hist<<<MARG_BLOCKS, 256, 0, stream>>>((const int4*)inputs, privMarg,
                                                  (uint32_t*)ws, zwords, P);
  scatter_marg<<<(P + 255) / 256, 256, 0, stream>>>((const int4*)inputs, tdims,
                                                    privMarg, HdNeg, gCursor, bdata,
                                                    P, T, invP);
  bucket_entropy_fin<<<T * BPT, 256, 0, stream>>>(bdata, gCursor, HjNeg, HdNeg,
                                                  tdims, done, T, invP, (float*)d_out);
}